// Round 1
// baseline (1295.176 us; speedup 1.0000x reference)
//
#include <hip/hip_runtime.h>
#include <stdint.h>

namespace {
constexpr int Bn  = 16;
constexpr int Cc  = 256;
constexpr int Hn  = 512;
constexpr int Tn  = 4096;
constexpr int CWn = Cc / 32;   // 8 words packed over C
constexpr int HWn = Hn / 32;   // 16 words packed over H
constexpr int TWn = Tn / 32;   // 128 words packed over T
constexpr float EPSf = 1e-5f;
}

// ---------------- setup: thresholds + packed sign weights --------------------
// thr = mean - beta*sqrt(var+eps)/gamma  (gamma>=0 => bn(v)>0 <=> v>thr;
// gamma==0 gives +-inf which selects the constant sign(beta) branch correctly)
__global__ __launch_bounds__(512) void setup_kernel(
    const float* __restrict__ bn1g, const float* __restrict__ bn1b,
    const float* __restrict__ bn1m, const float* __restrict__ bn1v,
    const float* __restrict__ w1,
    const float* __restrict__ bn2g, const float* __restrict__ bn2b,
    const float* __restrict__ bn2m, const float* __restrict__ bn2v,
    const float* __restrict__ dww,
    const float* __restrict__ bn3g, const float* __restrict__ bn3b,
    const float* __restrict__ bn3m, const float* __restrict__ bn3v,
    const float* __restrict__ w2,
    float* __restrict__ thr1, float* __restrict__ thr2, float* __restrict__ thr3,
    uint32_t* __restrict__ dws, uint32_t* __restrict__ W1p, uint32_t* __restrict__ W2p)
{
  const int i = blockIdx.x;      // repeat-block index 0..7
  const int tid = threadIdx.x;   // 0..511
  if (tid < Cc) {
    const int c = i * Cc + tid;
    thr1[c] = bn1m[c] - bn1b[c] * sqrtf(bn1v[c] + EPSf) / bn1g[c];
    // W2 sign bits packed over H:  W2p[c][w] bit j = sign(w2[i][c][w*32+j]) > 0
    for (int w = 0; w < HWn; ++w) {
      uint32_t word = 0;
      const float* src = w2 + (size_t)c * Hn + w * 32;
      for (int j = 0; j < 32; ++j) word |= (uint32_t)(src[j] > 0.f) << j;
      W2p[c * HWn + w] = word;
    }
  }
  {
    const int h = i * Hn + tid;
    thr2[h] = bn2m[h] - bn2b[h] * sqrtf(bn2v[h] + EPSf) / bn2g[h];
    thr3[h] = bn3m[h] - bn3b[h] * sqrtf(bn3v[h] + EPSf) / bn3g[h];
    uint32_t dw = 0;
    for (int k = 0; k < 3; ++k) dw |= (uint32_t)(dww[(size_t)h * 3 + k] > 0.f) << k;
    dws[h] = dw;
    // W1 sign bits packed over C:  W1p[h][w] bit j = sign(w1[i][h][w*32+j]) > 0
    for (int w = 0; w < CWn; ++w) {
      uint32_t word = 0;
      const float* src = w1 + (size_t)h * Cc + w * 32;
      for (int j = 0; j < 32; ++j) word |= (uint32_t)(src[j] > 0.f) << j;
      W1p[h * CWn + w] = word;
    }
  }
}

// --------------- K1: bn1 + sign + pack over C  (resid -> Xp) -----------------
// thread = (b, cw, t); lanes run over consecutive t => coalesced resid reads.
__global__ __launch_bounds__(256) void k1_pack(
    const float* __restrict__ resid, const float* __restrict__ thr1,
    uint32_t* __restrict__ Xp)
{
  const int idx = blockIdx.x * 256 + threadIdx.x;  // Bn*CWn*Tn threads
  const int t  = idx & (Tn - 1);
  const int cw = (idx >> 12) & (CWn - 1);
  const int b  = idx >> 15;
  const float* r = resid + ((size_t)(b * Cc + cw * 32)) * Tn + t;
  uint32_t word = 0;
#pragma unroll
  for (int j = 0; j < 32; ++j) {
    float v = r[(size_t)j * Tn];
    word |= (uint32_t)(v > thr1[cw * 32 + j]) << j;
  }
  Xp[((size_t)b * CWn + cw) * Tn + t] = word;
}

// --------- K2: binary GEMM1 (C->H) + bn2 + sign + pack over T (-> Y) ---------
// thread = (b, o-group-of-4, t). X words reused for 4 output channels.
__global__ __launch_bounds__(256) void k2_gemm1(
    const uint32_t* __restrict__ Xp, const uint32_t* __restrict__ W1p,
    const float* __restrict__ thr2, uint32_t* __restrict__ Y)
{
  const int idx = blockIdx.x * 256 + threadIdx.x;  // Bn*(Hn/4)*Tn threads
  const int t  = idx & (Tn - 1);
  const int og = (idx >> 12) & 127;
  const int b  = idx >> 19;
  const int o  = og * 4;
  int acc[4] = {0, 0, 0, 0};
  const uint32_t* xrow = Xp + (size_t)b * CWn * Tn + t;
  const uint32_t* wrow = W1p + o * CWn;
#pragma unroll
  for (int w = 0; w < CWn; ++w) {
    const uint32_t xw = xrow[(size_t)w * Tn];
    acc[0] += __popc(xw ^ wrow[0 * CWn + w]);
    acc[1] += __popc(xw ^ wrow[1 * CWn + w]);
    acc[2] += __popc(xw ^ wrow[2 * CWn + w]);
    acc[3] += __popc(xw ^ wrow[3 * CWn + w]);
  }
  const int lane = threadIdx.x & 63;
#pragma unroll
  for (int oo = 0; oo < 4; ++oo) {
    const float v = (float)(Cc - 2 * acc[oo]);
    const uint64_t m = __ballot(v > thr2[o + oo]);   // bit l <-> t0+l
    if ((lane & 31) == 0)
      Y[((size_t)b * Hn + o + oo) * TWn + (t >> 5)] = (uint32_t)(m >> lane);
  }
}

// ------ K3: depthwise dilated K=3 + bn3 + sign + pack over H (-> Z) ----------
// thread = (b, hw, t); loops 32 channels of its H-word, reads 3 bits each.
__global__ __launch_bounds__(256) void k3_dw(
    const uint32_t* __restrict__ Y, const uint32_t* __restrict__ dws,
    const float* __restrict__ thr3, uint32_t* __restrict__ Z, int dil)
{
  const int idx = blockIdx.x * 256 + threadIdx.x;  // Bn*HWn*Tn threads
  const int t  = idx & (Tn - 1);
  const int hw = (idx >> 12) & (HWn - 1);
  const int b  = idx >> 16;
  const bool hasL = (t >= dil);
  const bool hasR = (t + dil < Tn);
  const int tl = t - dil, tr = t + dil;
  uint32_t zw = 0;
#pragma unroll 8
  for (int j = 0; j < 32; ++j) {
    const int h = hw * 32 + j;
    const uint32_t* yr = Y + ((size_t)b * Hn + h) * TWn;
    const uint32_t d = dws[h];
    const int bc = (yr[t >> 5] >> (t & 31)) & 1;
    int s = (bc == (int)((d >> 1) & 1)) ? 1 : -1;
    if (hasL) { const int bl = (yr[tl >> 5] >> (tl & 31)) & 1; s += (bl == (int)(d & 1)) ? 1 : -1; }
    if (hasR) { const int br = (yr[tr >> 5] >> (tr & 31)) & 1; s += (br == (int)((d >> 2) & 1)) ? 1 : -1; }
    zw |= (uint32_t)((float)s > thr3[h]) << j;
  }
  Z[((size_t)b * HWn + hw) * Tn + t] = zw;
}

// --------- K4: binary GEMM2 (H->C) + residual add (rout = rin + h) -----------
// thread = (b, c-group-of-4, t). Z words reused for 4 output channels.
__global__ __launch_bounds__(256) void k4_gemm2(
    const uint32_t* __restrict__ Zp, const uint32_t* __restrict__ W2p,
    const float* __restrict__ rin, float* __restrict__ rout)
{
  const int idx = blockIdx.x * 256 + threadIdx.x;  // Bn*(Cc/4)*Tn threads
  const int t  = idx & (Tn - 1);
  const int cg = (idx >> 12) & 63;
  const int b  = idx >> 18;
  const int c  = cg * 4;
  int acc[4] = {0, 0, 0, 0};
  const uint32_t* zrow = Zp + (size_t)b * HWn * Tn + t;
  const uint32_t* wrow = W2p + c * HWn;
#pragma unroll
  for (int w = 0; w < HWn; ++w) {
    const uint32_t zw = zrow[(size_t)w * Tn];
    acc[0] += __popc(zw ^ wrow[0 * HWn + w]);
    acc[1] += __popc(zw ^ wrow[1 * HWn + w]);
    acc[2] += __popc(zw ^ wrow[2 * HWn + w]);
    acc[3] += __popc(zw ^ wrow[3 * HWn + w]);
  }
  const size_t base = ((size_t)b * Cc + c) * Tn + t;
#pragma unroll
  for (int cc = 0; cc < 4; ++cc)
    rout[base + (size_t)cc * Tn] = rin[base + (size_t)cc * Tn] + (float)(Hn - 2 * acc[cc]);
}

// ----------------------------------------------------------------------------
extern "C" void kernel_launch(void* const* d_in, const int* in_sizes, int n_in,
                              void* d_out, int out_size, void* d_ws, size_t ws_size,
                              hipStream_t stream)
{
  const float* x     = (const float*)d_in[0];
  const float* bn1g  = (const float*)d_in[1];
  const float* bn1b  = (const float*)d_in[2];
  const float* bn1m  = (const float*)d_in[3];
  const float* bn1v  = (const float*)d_in[4];
  const float* w1    = (const float*)d_in[5];
  const float* bn2g  = (const float*)d_in[6];
  const float* bn2b  = (const float*)d_in[7];
  const float* bn2m  = (const float*)d_in[8];
  const float* bn2v  = (const float*)d_in[9];
  const float* dww   = (const float*)d_in[10];
  const float* bn3g  = (const float*)d_in[11];
  const float* bn3b  = (const float*)d_in[12];
  const float* bn3m  = (const float*)d_in[13];
  const float* bn3v  = (const float*)d_in[14];
  const float* w2    = (const float*)d_in[15];
  float* out = (float*)d_out;

  // workspace carve-up (~10.6 MB total)
  char* ws = (char*)d_ws;
  uint32_t* Xp  = (uint32_t*)(ws);                        // 16*8*4096*4   = 2 MB
  uint32_t* Y   = (uint32_t*)(ws + (2u  << 20));          // 16*512*128*4  = 4 MB
  uint32_t* Zp  = (uint32_t*)(ws + (6u  << 20));          // 16*16*4096*4  = 4 MB
  uint32_t* W1p = (uint32_t*)(ws + (10u << 20));          // 8*512*8*4  = 128 KB
  uint32_t* W2p = (uint32_t*)(ws + (10u << 20) + (128u << 10)); // 128 KB
  float*    thr1 = (float*)(ws + (10u << 20) + (256u << 10));   // 8*256*4
  float*    thr2 = thr1 + 8 * Cc;                               // 8*512*4
  float*    thr3 = thr2 + 8 * Hn;                               // 8*512*4
  uint32_t* dws  = (uint32_t*)(thr3 + 8 * Hn);                  // 8*512*4

  setup_kernel<<<8, 512, 0, stream>>>(bn1g, bn1b, bn1m, bn1v, w1,
                                      bn2g, bn2b, bn2m, bn2v, dww,
                                      bn3g, bn3b, bn3m, bn3v, w2,
                                      thr1, thr2, thr3, dws, W1p, W2p);

  for (int i = 0; i < 8; ++i) {
    const float* rin = (i == 0) ? x : out;
    k1_pack <<<2048,  256, 0, stream>>>(rin, thr1 + i * Cc, Xp);
    k2_gemm1<<<32768, 256, 0, stream>>>(Xp, W1p + i * Hn * CWn, thr2 + i * Hn, Y);
    k3_dw   <<<4096,  256, 0, stream>>>(Y, dws + i * Hn, thr3 + i * Hn, Zp, 1 << i);
    k4_gemm2<<<16384, 256, 0, stream>>>(Zp, W2p + i * Cc * HWn, rin, out);
  }
}

// Round 2
// 774.299 us; speedup vs baseline: 1.6727x; 1.6727x over previous
//
#include <hip/hip_runtime.h>
#include <stdint.h>

namespace {
constexpr int Bn  = 16;
constexpr int Cc  = 256;
constexpr int Hn  = 512;
constexpr int Tn  = 4096;
constexpr int CWn = Cc / 32;   // 8 words packed over C
constexpr int HWn = Hn / 32;   // 16 words packed over H
constexpr int TWn = Tn / 32;   // 128 words packed over T
constexpr float EPSf = 1e-5f;
}

// ---------------- setup: thresholds + packed sign weights --------------------
// thr = mean - beta*sqrt(var+eps)/gamma  (gamma>=0 => bn(v)>0 <=> v>thr;
// gamma==0 gives +-inf which selects the constant sign(beta) branch correctly)
__global__ __launch_bounds__(256) void setup_kernel(
    const float* __restrict__ bn1g, const float* __restrict__ bn1b,
    const float* __restrict__ bn1m, const float* __restrict__ bn1v,
    const float* __restrict__ w1,
    const float* __restrict__ bn2g, const float* __restrict__ bn2b,
    const float* __restrict__ bn2m, const float* __restrict__ bn2v,
    const float* __restrict__ dww,
    const float* __restrict__ bn3g, const float* __restrict__ bn3b,
    const float* __restrict__ bn3m, const float* __restrict__ bn3v,
    const float* __restrict__ w2,
    float* __restrict__ thr1, float* __restrict__ thr2, float* __restrict__ thr3,
    uint32_t* __restrict__ dws, uint32_t* __restrict__ W1p, uint32_t* __restrict__ W2p)
{
  const int idx = blockIdx.x * 256 + threadIdx.x;  // 65536 threads
  if (idx < 8 * Hn * CWn) {                        // W1 words: 32768
    const int w = idx & (CWn - 1);
    const int h = idx >> 3;                        // global h 0..4095
    const float* src = w1 + (size_t)h * Cc + w * 32;
    uint32_t word = 0;
#pragma unroll
    for (int j = 0; j < 32; ++j) word |= (uint32_t)(src[j] > 0.f) << j;
    W1p[h * CWn + w] = word;
  } else {                                         // W2 words: 32768
    const int k = idx - 8 * Hn * CWn;
    const int w = k & (HWn - 1);
    const int c = k >> 4;                          // global c 0..2047
    const float* src = w2 + (size_t)c * Hn + w * 32;
    uint32_t word = 0;
#pragma unroll
    for (int j = 0; j < 32; ++j) word |= (uint32_t)(src[j] > 0.f) << j;
    W2p[c * HWn + w] = word;
  }
  if (idx < 8 * Cc)
    thr1[idx] = bn1m[idx] - bn1b[idx] * sqrtf(bn1v[idx] + EPSf) / bn1g[idx];
  if (idx < 8 * Hn) {
    thr2[idx] = bn2m[idx] - bn2b[idx] * sqrtf(bn2v[idx] + EPSf) / bn2g[idx];
    thr3[idx] = bn3m[idx] - bn3b[idx] * sqrtf(bn3v[idx] + EPSf) / bn3g[idx];
    uint32_t dw = 0;
    for (int k = 0; k < 3; ++k) dw |= (uint32_t)(dww[(size_t)idx * 3 + k] > 0.f) << k;
    dws[idx] = dw;
  }
}

// --------------- K1: bn1 + sign + pack over C  (x -> Xp), i=0 only -----------
__global__ __launch_bounds__(256) void k1_pack(
    const float* __restrict__ resid, const float* __restrict__ thr1,
    uint32_t* __restrict__ Xp)
{
  const int idx = blockIdx.x * 256 + threadIdx.x;  // Bn*CWn*Tn threads
  const int t  = idx & (Tn - 1);
  const int cw = (idx >> 12) & (CWn - 1);
  const int b  = idx >> 15;
  const float* r = resid + ((size_t)(b * Cc + cw * 32)) * Tn + t;
  uint32_t word = 0;
#pragma unroll
  for (int j = 0; j < 32; ++j)
    word |= (uint32_t)(r[(size_t)j * Tn] > thr1[cw * 32 + j]) << j;
  Xp[((size_t)b * CWn + cw) * Tn + t] = word;
}

// --------- K2: binary GEMM1 (C->H) + bn2 + sign + pack over T (-> Y) ---------
// Y layout: [b][tw][h] so k3's lane-over-channel reads coalesce.
__global__ __launch_bounds__(256) void k2_gemm1(
    const uint32_t* __restrict__ Xp, const uint32_t* __restrict__ W1p,
    const float* __restrict__ thr2, uint32_t* __restrict__ Y)
{
  const int idx = blockIdx.x * 256 + threadIdx.x;  // Bn*(Hn/4)*Tn threads
  const int t  = idx & (Tn - 1);
  const int og = (idx >> 12) & 127;
  const int b  = idx >> 19;
  const int o  = og * 4;
  int acc[4] = {0, 0, 0, 0};
  const uint32_t* xrow = Xp + (size_t)b * CWn * Tn + t;
  const uint32_t* wrow = W1p + o * CWn;
#pragma unroll
  for (int w = 0; w < CWn; ++w) {
    const uint32_t xw = xrow[(size_t)w * Tn];
    acc[0] += __popc(xw ^ wrow[0 * CWn + w]);
    acc[1] += __popc(xw ^ wrow[1 * CWn + w]);
    acc[2] += __popc(xw ^ wrow[2 * CWn + w]);
    acc[3] += __popc(xw ^ wrow[3 * CWn + w]);
  }
  const int lane = threadIdx.x & 63;
#pragma unroll
  for (int oo = 0; oo < 4; ++oo) {
    const float v = (float)(Cc - 2 * acc[oo]);
    const uint64_t m = __ballot(v > thr2[o + oo]);   // bit l <-> t0+l
    if ((lane & 31) == 0)
      Y[((size_t)b * TWn + (t >> 5)) * Hn + o + oo] = (uint32_t)(m >> lane);
  }
}

// ------ K3: depthwise dilated K=3 + bn3 + sign, word-parallel bit logic ------
// Wave: 32 channels (one hw word) x 2 t-words; majority logic per word, then
// 32x32 bit transpose per half-wave -> H-packed Z[b][hw][t].
__global__ __launch_bounds__(256) void k3_dw(
    const uint32_t* __restrict__ Y, const uint32_t* __restrict__ dws,
    const float* __restrict__ thr3, uint32_t* __restrict__ Z, int dil)
{
  const int wv = (blockIdx.x << 2) + (threadIdx.x >> 6);  // Bn*HWn*TWn/2 waves
  const int lane = threadIdx.x & 63;
  const int lh = lane & 31;
  const int tpair = wv & (TWn / 2 - 1);
  const int hw = (wv >> 6) & (HWn - 1);
  const int b  = wv >> 10;
  const int tw = tpair * 2 + (lane >> 5);
  const int ch = hw * 32 + lh;

  const uint32_t* yb = Y + (size_t)b * TWn * Hn + ch;
  const uint32_t ycur = yb[(size_t)tw * Hn];
  uint32_t yl, yr, Vl, Vr;
  if (dil >= 32) {
    const int dw = dil >> 5;
    const bool lok = tw >= dw, rok = tw + dw < TWn;
    yl = lok ? yb[(size_t)(tw - dw) * Hn] : 0u;
    yr = rok ? yb[(size_t)(tw + dw) * Hn] : 0u;
    Vl = lok ? ~0u : 0u;
    Vr = rok ? ~0u : 0u;
  } else {
    const uint32_t yp = (tw > 0) ? yb[(size_t)(tw - 1) * Hn] : 0u;
    const uint32_t yn = (tw < TWn - 1) ? yb[(size_t)(tw + 1) * Hn] : 0u;
    yl = (ycur << dil) | ((tw > 0) ? (yp >> (32 - dil)) : 0u);
    yr = (ycur >> dil) | ((tw < TWn - 1) ? (yn << (32 - dil)) : 0u);
    Vl = (tw == 0) ? (~0u << dil) : ~0u;
    Vr = (tw == TWn - 1) ? (~0u >> dil) : ~0u;
  }
  const uint32_t d = dws[ch];
  const uint32_t a  = ((d & 1u) ? yl : ~yl) & Vl;      // left-tap match (valid)
  const uint32_t bb = (d & 2u) ? ycur : ~ycur;         // center match
  const uint32_t c  = ((d & 4u) ? yr : ~yr) & Vr;      // right-tap match (valid)

  // s = 2*matches - present_taps > thr  <=>  matches >= K_p
  const float thr = thr3[ch];
  const float v3 = (thr + 3.f) * 0.5f;
  const float v2 = (thr + 2.f) * 0.5f;
  const int K3 = (int)(v3 >= 0.f) + (int)(v3 >= 1.f) + (int)(v3 >= 2.f) + (int)(v3 >= 3.f);
  const int K2 = (int)(v2 >= 0.f) + (int)(v2 >= 1.f) + (int)(v2 >= 2.f);

  const uint32_t g1 = a | bb | c;
  const uint32_t g2 = (a & bb) | (c & (a | bb));
  const uint32_t g3 = a & bb & c;
  const uint32_t full = (K3 == 0) ? ~0u : (K3 == 1) ? g1 : (K3 == 2) ? g2
                      : (K3 == 3) ? g3 : 0u;
  const uint32_t lm = (K2 == 0) ? ~0u : (K2 == 1) ? (bb | c) : (K2 == 2) ? (bb & c) : 0u;
  const uint32_t rm = (K2 == 0) ? ~0u : (K2 == 1) ? (a | bb) : (K2 == 2) ? (a & bb) : 0u;

  uint32_t w = (Vl & Vr & full) | (~Vl & lm) | (~Vr & rm);

  // 32x32 bit transpose within each half-wave: after this, lane lh holds the
  // word for t = tw*32+lh with bit j = channel hw*32+j.
#pragma unroll
  for (int s = 16; s; s >>= 1) {
    const uint32_t m = 0xFFFFFFFFu / ((1u << s) + 1u);  // bits with (c&s)==0
    const uint32_t o = __shfl_xor(w, s, 64);
    w = ((lane & s) == 0) ? ((w & m) | ((o & m) << s))
                          : ((w & ~m) | ((o & ~m) >> s));
  }
  Z[((size_t)b * HWn + hw) * Tn + tw * 32 + lh] = w;
}

// --- K4: binary GEMM2 (H->C) + residual add + bn1/sign/pack for next block ---
// thread = (b, cw, t): 32 output channels; emits next iteration's Xp word.
__global__ __launch_bounds__(256) void k4_gemm2(
    const uint32_t* __restrict__ Zp, const uint32_t* __restrict__ W2p,
    const float* __restrict__ rin, float* __restrict__ rout,
    const float* __restrict__ thr1n, uint32_t* __restrict__ Xp)
{
  const int idx = blockIdx.x * 256 + threadIdx.x;  // Bn*CWn*Tn threads
  const int t  = idx & (Tn - 1);
  const int cw = (idx >> 12) & (CWn - 1);
  const int b  = idx >> 15;
  uint32_t zw[HWn];
  const uint32_t* zrow = Zp + (size_t)b * HWn * Tn + t;
#pragma unroll
  for (int w = 0; w < HWn; ++w) zw[w] = zrow[(size_t)w * Tn];
  const uint32_t* wrow = W2p + (cw * 32) * HWn;
  const size_t base = ((size_t)(b * Cc + cw * 32)) * Tn + t;
  uint32_t word = 0;
#pragma unroll
  for (int j = 0; j < 32; ++j) {
    int acc = 0;
#pragma unroll
    for (int w = 0; w < HWn; ++w) acc += __popc(zw[w] ^ wrow[j * HWn + w]);
    const float ro = rin[base + (size_t)j * Tn] + (float)(Hn - 2 * acc);
    rout[base + (size_t)j * Tn] = ro;
    word |= (uint32_t)(ro > thr1n[cw * 32 + j]) << j;
  }
  Xp[((size_t)b * CWn + cw) * Tn + t] = word;
}

// ----------------------------------------------------------------------------
extern "C" void kernel_launch(void* const* d_in, const int* in_sizes, int n_in,
                              void* d_out, int out_size, void* d_ws, size_t ws_size,
                              hipStream_t stream)
{
  const float* x     = (const float*)d_in[0];
  const float* bn1g  = (const float*)d_in[1];
  const float* bn1b  = (const float*)d_in[2];
  const float* bn1m  = (const float*)d_in[3];
  const float* bn1v  = (const float*)d_in[4];
  const float* w1    = (const float*)d_in[5];
  const float* bn2g  = (const float*)d_in[6];
  const float* bn2b  = (const float*)d_in[7];
  const float* bn2m  = (const float*)d_in[8];
  const float* bn2v  = (const float*)d_in[9];
  const float* dww   = (const float*)d_in[10];
  const float* bn3g  = (const float*)d_in[11];
  const float* bn3b  = (const float*)d_in[12];
  const float* bn3m  = (const float*)d_in[13];
  const float* bn3v  = (const float*)d_in[14];
  const float* w2    = (const float*)d_in[15];
  float* out = (float*)d_out;

  // workspace carve-up (~10.6 MB total)
  char* ws = (char*)d_ws;
  uint32_t* Xp  = (uint32_t*)(ws);                        // 2 MB
  uint32_t* Y   = (uint32_t*)(ws + (2u  << 20));          // 4 MB  [b][tw][h]
  uint32_t* Zp  = (uint32_t*)(ws + (6u  << 20));          // 4 MB  [b][hw][t]
  uint32_t* W1p = (uint32_t*)(ws + (10u << 20));          // 128 KB
  uint32_t* W2p = (uint32_t*)(ws + (10u << 20) + (128u << 10)); // 128 KB
  float*    thr1 = (float*)(ws + (10u << 20) + (256u << 10));
  float*    thr2 = thr1 + 8 * Cc;
  float*    thr3 = thr2 + 8 * Hn;
  uint32_t* dws  = (uint32_t*)(thr3 + 8 * Hn);

  setup_kernel<<<256, 256, 0, stream>>>(bn1g, bn1b, bn1m, bn1v, w1,
                                        bn2g, bn2b, bn2m, bn2v, dww,
                                        bn3g, bn3b, bn3m, bn3v, w2,
                                        thr1, thr2, thr3, dws, W1p, W2p);

  k1_pack<<<2048, 256, 0, stream>>>(x, thr1, Xp);

  for (int i = 0; i < 8; ++i) {
    const float* rin = (i == 0) ? x : out;
    const int inext = (i < 7) ? i + 1 : 7;
    k2_gemm1<<<32768, 256, 0, stream>>>(Xp, W1p + i * Hn * CWn, thr2 + i * Hn, Y);
    k3_dw   <<<4096,  256, 0, stream>>>(Y, dws + i * Hn, thr3 + i * Hn, Zp, 1 << i);
    k4_gemm2<<<2048,  256, 0, stream>>>(Zp, W2p + i * Cc * HWn, rin, out,
                                        thr1 + inext * Cc, Xp);
  }
}

// Round 3
// 492.362 us; speedup vs baseline: 2.6305x; 1.5726x over previous
//
#include <hip/hip_runtime.h>
#include <stdint.h>

namespace {
constexpr int Bn  = 16;
constexpr int Cc  = 256;
constexpr int Hn  = 512;
constexpr int Tn  = 4096;
constexpr int CWn = Cc / 32;   // 8 words packed over C
constexpr int HWn = Hn / 32;   // 16 words packed over H
constexpr int TWn = Tn / 32;   // 128 words packed over T
constexpr float EPSf = 1e-5f;
}

// ---------------- setup: thresholds + packed sign weights --------------------
// thr = mean - beta*sqrt(var+eps)/gamma  (gamma>=0 => bn(v)>0 <=> v>thr;
// gamma==0 gives +-inf which selects the constant sign(beta) branch correctly)
__global__ __launch_bounds__(256) void setup_kernel(
    const float* __restrict__ bn1g, const float* __restrict__ bn1b,
    const float* __restrict__ bn1m, const float* __restrict__ bn1v,
    const float* __restrict__ w1,
    const float* __restrict__ bn2g, const float* __restrict__ bn2b,
    const float* __restrict__ bn2m, const float* __restrict__ bn2v,
    const float* __restrict__ dww,
    const float* __restrict__ bn3g, const float* __restrict__ bn3b,
    const float* __restrict__ bn3m, const float* __restrict__ bn3v,
    const float* __restrict__ w2,
    float* __restrict__ thr1, float* __restrict__ thr2, float* __restrict__ thr3,
    uint32_t* __restrict__ dws, uint32_t* __restrict__ W1p, uint32_t* __restrict__ W2p)
{
  const int idx = blockIdx.x * 256 + threadIdx.x;  // 65536 threads
  if (idx < 8 * Hn * CWn) {                        // W1 words: 32768
    const int w = idx & (CWn - 1);
    const int h = idx >> 3;                        // global h 0..4095
    const float* src = w1 + (size_t)h * Cc + w * 32;
    uint32_t word = 0;
#pragma unroll
    for (int j = 0; j < 32; ++j) word |= (uint32_t)(src[j] > 0.f) << j;
    W1p[h * CWn + w] = word;
  } else {                                         // W2 words: 32768
    const int k = idx - 8 * Hn * CWn;
    const int w = k & (HWn - 1);
    const int c = k >> 4;                          // global c 0..2047
    const float* src = w2 + (size_t)c * Hn + w * 32;
    uint32_t word = 0;
#pragma unroll
    for (int j = 0; j < 32; ++j) word |= (uint32_t)(src[j] > 0.f) << j;
    W2p[c * HWn + w] = word;
  }
  if (idx < 8 * Cc)
    thr1[idx] = bn1m[idx] - bn1b[idx] * sqrtf(bn1v[idx] + EPSf) / bn1g[idx];
  if (idx < 8 * Hn) {
    thr2[idx] = bn2m[idx] - bn2b[idx] * sqrtf(bn2v[idx] + EPSf) / bn2g[idx];
    thr3[idx] = bn3m[idx] - bn3b[idx] * sqrtf(bn3v[idx] + EPSf) / bn3g[idx];
    uint32_t dw = 0;
    for (int k = 0; k < 3; ++k) dw |= (uint32_t)(dww[(size_t)idx * 3 + k] > 0.f) << k;
    dws[idx] = dw;
  }
}

// --------------- K1: bn1 + sign + pack over C  (x -> Xp), i=0 only -----------
__global__ __launch_bounds__(256) void k1_pack(
    const float* __restrict__ resid, const float* __restrict__ thr1,
    uint32_t* __restrict__ Xp)
{
  const int idx = blockIdx.x * 256 + threadIdx.x;  // Bn*CWn*Tn threads
  const int t  = idx & (Tn - 1);
  const int cw = (idx >> 12) & (CWn - 1);
  const int b  = idx >> 15;
  const float* r = resid + ((size_t)(b * Cc + cw * 32)) * Tn + t;
  uint32_t word = 0;
#pragma unroll
  for (int j = 0; j < 32; ++j)
    word |= (uint32_t)(r[(size_t)j * Tn] > thr1[cw * 32 + j]) << j;
  Xp[((size_t)b * CWn + cw) * Tn + t] = word;
}

// --------- K2: binary GEMM1 (C->H) + bn2 + sign + pack over T (-> Y) ---------
// Block-uniform (b, og, tblk) from blockIdx only => W1 rows scalarize to
// s_load/SGPRs; thread covers 8 output channels; lanes run over t.
// Y layout: [b][tw][h] so k3's lane-over-channel reads coalesce.
__global__ __launch_bounds__(256) void k2_gemm1(
    const uint32_t* __restrict__ Xp, const uint32_t* __restrict__ W1p,
    const float* __restrict__ thr2, uint32_t* __restrict__ Y)
{
  const int bid  = blockIdx.x;          // b(16) x og(64) x tblk(16)
  const int tblk = bid & 15;
  const int og   = (bid >> 4) & 63;
  const int b    = bid >> 10;
  const int t    = tblk * 256 + threadIdx.x;
  const int o    = og * 8;

  const uint32_t* xrow = Xp + (size_t)b * CWn * Tn + t;
  const uint32_t* wrow = W1p + o * CWn;     // uniform -> scalar loads
  int acc[8] = {0, 0, 0, 0, 0, 0, 0, 0};
#pragma unroll
  for (int w = 0; w < CWn; ++w) {
    const uint32_t xw = xrow[(size_t)w * Tn];
#pragma unroll
    for (int r = 0; r < 8; ++r)
      acc[r] += __popc(xw ^ wrow[r * CWn + w]);
  }
  const int lane = threadIdx.x & 63;
#pragma unroll
  for (int r = 0; r < 8; ++r) {
    const float v = (float)(Cc - 2 * acc[r]);
    const uint64_t m = __ballot(v > thr2[o + r]);   // bit l <-> lane l
    if ((lane & 31) == 0)
      Y[((size_t)b * TWn + (t >> 5)) * Hn + o + r] = (uint32_t)(m >> lane);
  }
}

// ------ K3: depthwise dilated K=3 + bn3 + sign, word-parallel bit logic ------
// Wave: 32 channels (one hw word) x 2 t-words; majority logic per word, then
// 32x32 bit transpose per half-wave -> H-packed Z[b][hw][t].
__global__ __launch_bounds__(256) void k3_dw(
    const uint32_t* __restrict__ Y, const uint32_t* __restrict__ dws,
    const float* __restrict__ thr3, uint32_t* __restrict__ Z, int dil)
{
  const int wv = (blockIdx.x << 2) + (threadIdx.x >> 6);  // Bn*HWn*TWn/2 waves
  const int lane = threadIdx.x & 63;
  const int lh = lane & 31;
  const int tpair = wv & (TWn / 2 - 1);
  const int hw = (wv >> 6) & (HWn - 1);
  const int b  = wv >> 10;
  const int tw = tpair * 2 + (lane >> 5);
  const int ch = hw * 32 + lh;

  const uint32_t* yb = Y + (size_t)b * TWn * Hn + ch;
  const uint32_t ycur = yb[(size_t)tw * Hn];
  uint32_t yl, yr, Vl, Vr;
  if (dil >= 32) {
    const int dw = dil >> 5;
    const bool lok = tw >= dw, rok = tw + dw < TWn;
    yl = lok ? yb[(size_t)(tw - dw) * Hn] : 0u;
    yr = rok ? yb[(size_t)(tw + dw) * Hn] : 0u;
    Vl = lok ? ~0u : 0u;
    Vr = rok ? ~0u : 0u;
  } else {
    const uint32_t yp = (tw > 0) ? yb[(size_t)(tw - 1) * Hn] : 0u;
    const uint32_t yn = (tw < TWn - 1) ? yb[(size_t)(tw + 1) * Hn] : 0u;
    yl = (ycur << dil) | ((tw > 0) ? (yp >> (32 - dil)) : 0u);
    yr = (ycur >> dil) | ((tw < TWn - 1) ? (yn << (32 - dil)) : 0u);
    Vl = (tw == 0) ? (~0u << dil) : ~0u;
    Vr = (tw == TWn - 1) ? (~0u >> dil) : ~0u;
  }
  const uint32_t d = dws[ch];
  const uint32_t a  = ((d & 1u) ? yl : ~yl) & Vl;      // left-tap match (valid)
  const uint32_t bb = (d & 2u) ? ycur : ~ycur;         // center match
  const uint32_t c  = ((d & 4u) ? yr : ~yr) & Vr;      // right-tap match (valid)

  // s = 2*matches - present_taps > thr  <=>  matches >= K_p
  const float thr = thr3[ch];
  const float v3 = (thr + 3.f) * 0.5f;
  const float v2 = (thr + 2.f) * 0.5f;
  const int K3 = (int)(v3 >= 0.f) + (int)(v3 >= 1.f) + (int)(v3 >= 2.f) + (int)(v3 >= 3.f);
  const int K2 = (int)(v2 >= 0.f) + (int)(v2 >= 1.f) + (int)(v2 >= 2.f);

  const uint32_t g1 = a | bb | c;
  const uint32_t g2 = (a & bb) | (c & (a | bb));
  const uint32_t g3 = a & bb & c;
  const uint32_t full = (K3 == 0) ? ~0u : (K3 == 1) ? g1 : (K3 == 2) ? g2
                      : (K3 == 3) ? g3 : 0u;
  const uint32_t lm = (K2 == 0) ? ~0u : (K2 == 1) ? (bb | c) : (K2 == 2) ? (bb & c) : 0u;
  const uint32_t rm = (K2 == 0) ? ~0u : (K2 == 1) ? (a | bb) : (K2 == 2) ? (a & bb) : 0u;

  uint32_t w = (Vl & Vr & full) | (~Vl & lm) | (~Vr & rm);

  // 32x32 bit transpose within each half-wave: after this, lane lh holds the
  // word for t = tw*32+lh with bit j = channel hw*32+j.
#pragma unroll
  for (int s = 16; s; s >>= 1) {
    const uint32_t m = 0xFFFFFFFFu / ((1u << s) + 1u);  // bits with (c&s)==0
    const uint32_t o = __shfl_xor(w, s, 64);
    w = ((lane & s) == 0) ? ((w & m) | ((o & m) << s))
                          : ((w & ~m) | ((o & ~m) >> s));
  }
  Z[((size_t)b * HWn + hw) * Tn + tw * 32 + lh] = w;
}

// --- K4: binary GEMM2 (H->C) + residual add + bn1/sign/pack for next block ---
// Block-uniform (b, cw, tblk) => W2 rows scalarize; j-loop chunked by 4 rows
// (64 uniform dwords/chunk) to bound SGPR pressure. Emits next block's Xp.
__global__ __launch_bounds__(256) void k4_gemm2(
    const uint32_t* __restrict__ Zp, const uint32_t* __restrict__ W2p,
    const float* __restrict__ rin, float* __restrict__ rout,
    const float* __restrict__ thr1n, uint32_t* __restrict__ Xp)
{
  const int bid  = blockIdx.x;          // b(16) x cw(8) x tblk(16)
  const int tblk = bid & 15;
  const int cw   = (bid >> 4) & 7;
  const int b    = bid >> 7;
  const int t    = tblk * 256 + threadIdx.x;

  uint32_t zw[HWn];
  const uint32_t* zrow = Zp + (size_t)b * HWn * Tn + t;
#pragma unroll
  for (int w = 0; w < HWn; ++w) zw[w] = zrow[(size_t)w * Tn];

  const uint32_t* wrow = W2p + (cw * 32) * HWn;   // uniform -> scalar loads
  const size_t base = ((size_t)(b * Cc + cw * 32)) * Tn + t;
  uint32_t word = 0;
#pragma unroll 1
  for (int jo = 0; jo < 32; jo += 4) {
#pragma unroll
    for (int jj = 0; jj < 4; ++jj) {
      const int j = jo + jj;
      int acc = 0;
#pragma unroll
      for (int w = 0; w < HWn; ++w) acc += __popc(zw[w] ^ wrow[j * HWn + w]);
      const float ro = rin[base + (size_t)j * Tn] + (float)(Hn - 2 * acc);
      rout[base + (size_t)j * Tn] = ro;
      word |= (uint32_t)(ro > thr1n[cw * 32 + j]) << j;
    }
  }
  Xp[((size_t)b * CWn + cw) * Tn + t] = word;
}

// ----------------------------------------------------------------------------
extern "C" void kernel_launch(void* const* d_in, const int* in_sizes, int n_in,
                              void* d_out, int out_size, void* d_ws, size_t ws_size,
                              hipStream_t stream)
{
  const float* x     = (const float*)d_in[0];
  const float* bn1g  = (const float*)d_in[1];
  const float* bn1b  = (const float*)d_in[2];
  const float* bn1m  = (const float*)d_in[3];
  const float* bn1v  = (const float*)d_in[4];
  const float* w1    = (const float*)d_in[5];
  const float* bn2g  = (const float*)d_in[6];
  const float* bn2b  = (const float*)d_in[7];
  const float* bn2m  = (const float*)d_in[8];
  const float* bn2v  = (const float*)d_in[9];
  const float* dww   = (const float*)d_in[10];
  const float* bn3g  = (const float*)d_in[11];
  const float* bn3b  = (const float*)d_in[12];
  const float* bn3m  = (const float*)d_in[13];
  const float* bn3v  = (const float*)d_in[14];
  const float* w2    = (const float*)d_in[15];
  float* out = (float*)d_out;

  // workspace carve-up (~10.6 MB total)
  char* ws = (char*)d_ws;
  uint32_t* Xp  = (uint32_t*)(ws);                        // 2 MB
  uint32_t* Y   = (uint32_t*)(ws + (2u  << 20));          // 4 MB  [b][tw][h]
  uint32_t* Zp  = (uint32_t*)(ws + (6u  << 20));          // 4 MB  [b][hw][t]
  uint32_t* W1p = (uint32_t*)(ws + (10u << 20));          // 128 KB
  uint32_t* W2p = (uint32_t*)(ws + (10u << 20) + (128u << 10)); // 128 KB
  float*    thr1 = (float*)(ws + (10u << 20) + (256u << 10));
  float*    thr2 = thr1 + 8 * Cc;
  float*    thr3 = thr2 + 8 * Hn;
  uint32_t* dws  = (uint32_t*)(thr3 + 8 * Hn);

  setup_kernel<<<256, 256, 0, stream>>>(bn1g, bn1b, bn1m, bn1v, w1,
                                        bn2g, bn2b, bn2m, bn2v, dww,
                                        bn3g, bn3b, bn3m, bn3v, w2,
                                        thr1, thr2, thr3, dws, W1p, W2p);

  k1_pack<<<2048, 256, 0, stream>>>(x, thr1, Xp);

  for (int i = 0; i < 8; ++i) {
    const float* rin = (i == 0) ? x : out;
    const int inext = (i < 7) ? i + 1 : 7;
    k2_gemm1<<<16384, 256, 0, stream>>>(Xp, W1p + i * Hn * CWn, thr2 + i * Hn, Y);
    k3_dw   <<<4096,  256, 0, stream>>>(Y, dws + i * Hn, thr3 + i * Hn, Zp, 1 << i);
    k4_gemm2<<<2048,  256, 0, stream>>>(Zp, W2p + i * Cc * HWn, rin, out,
                                        thr1 + inext * Cc, Xp);
  }
}